// Round 9
// baseline (482.914 us; speedup 1.0000x reference)
//
#include <hip/hip_runtime.h>
#include <hip/hip_cooperative_groups.h>

namespace cg = cooperative_groups;

// GCN_72971494359045: 2-layer GCNConv(+self-loops, sym-norm) with PReLU.
// N=50000 nodes, E=800000 edges, dims 128(+8 id)->256->128, all fp32.
//
// R17: gemm/aggs reverted to R10-exact (best verified: gemm 49.2us,
// agg<0> ~34us at the ~6TB/s gather floor, total 256.4us). The 7 small
// CSR/prep/post launches (the remaining ~138us incl. boundaries) collapse
// into ONE cooperative kernel with grid.sync() between dependent phases.
// All phase bodies verbatim (identical FP order) -> absmax canary
// 0.001953125. Launches 10 -> 4.

constexpr int NN = 50000;
constexpr int NE = 800000;
constexpr int NBUCK = 196;   // ceil(NN / 256), bucket = dst >> 8
constexpr int TILE = 2048;   // edges per scatter block
constexpr int NSCAT = (NE + TILE - 1) / TILE;  // 391
constexpr int GTH = NSCAT * 256;               // coop grid threads = 100096

typedef __attribute__((ext_vector_type(8))) short short8;
typedef __attribute__((ext_vector_type(4))) float floatx4;

__device__ inline void bsplit(float v, unsigned short& hi, unsigned short& lo) {
  unsigned u = __float_as_uint(v);
  hi = (unsigned short)(u >> 16);
  float rem = v - __uint_as_float(u & 0xffff0000u);
  lo = (unsigned short)(__float_as_uint(rem) >> 16);
}

__device__ inline unsigned short bf16_rtne(float v) {
  unsigned u = __float_as_uint(v);
  return (unsigned short)((u + 0x7fffu + ((u >> 16) & 1u)) >> 16);
}

__device__ inline float bflo(unsigned u) { return __uint_as_float(u << 16); }
__device__ inline float bfhi(unsigned u) { return __uint_as_float(u & 0xffff0000u); }

// Pack W[K x N] (fp32, row-major) into MFMA B-fragment order, split hi/lo.
template <int K, int N>
__device__ inline void pack_one(const float* __restrict__ W, unsigned short* __restrict__ Bhi,
                                unsigned short* __restrict__ Blo, int id) {
  constexpr int KC = K / 32;
  int j = id & 7;
  int lane = (id >> 3) & 63;
  int rest = id >> 9;
  int c = rest % KC;
  int nt = rest / KC;
  int k = c * 32 + (lane >> 4) * 8 + j;
  int n = nt * 16 + (lane & 15);
  unsigned short hi, lo;
  bsplit(W[(size_t)k * N + n], hi, lo);
  Bhi[id] = hi;
  Blo[id] = lo;
}

// One cooperative kernel: prep_weights + binned CSR build + post_csr.
// Phases (grid.sync between dependent ones); each phase body is the verbatim
// code of the former standalone kernel (same FP order, same per-item work).
__global__ __launch_bounds__(256) void build_kernel(
    const int* __restrict__ ei, const float* __restrict__ x,
    const float* __restrict__ W1, const float* __restrict__ W2,
    const float* __restrict__ idv,
    int* __restrict__ tilecnt, int* __restrict__ tpre, int* __restrict__ bbase,
    int* __restrict__ bcnt, unsigned* __restrict__ ebuf,
    int* __restrict__ offs, int* __restrict__ col, float* __restrict__ dinv,
    unsigned short* __restrict__ xsb, float* __restrict__ Svec,
    unsigned short* __restrict__ B1hi, unsigned short* __restrict__ B1lo,
    unsigned short* __restrict__ B2hi, unsigned short* __restrict__ B2lo,
    float* __restrict__ cvec) {
  cg::grid_group grid = cg::this_grid();
  __shared__ __attribute__((aligned(16))) char shraw[12288];
  int t = threadIdx.x;
  int blk = blockIdx.x;

  // ---- P0: prep_weights (independent; grid-stride) ----
  for (int id = blk * 256 + t; id < 65536 + 256; id += GTH) {
    if (id < 32768) {
      pack_one<128, 256>(W1, B1hi, B1lo, id);
    } else if (id < 65536) {
      pack_one<256, 128>(W2, B2hi, B2lo, id - 32768);
    } else {
      int m = id - 65536;
      float c = 0.f;
#pragma unroll
      for (int j = 0; j < 8; ++j) c += idv[j] * W1[(128 + j) * 256 + m];
      cvec[m] = c;
    }
  }

  // ---- P1: tile_count (one block per tile) ----
  {
    int* h = (int*)shraw;
    for (int i = t; i < NBUCK; i += 256) h[i] = 0;
    __syncthreads();
    int base = blk * TILE;
    int end = base + TILE; if (end > NE) end = NE;
    for (int e = base + t; e < end; e += 256) atomicAdd(&h[ei[NE + e] >> 8], 1);
    __syncthreads();
    for (int i = t; i < NBUCK; i += 256) tilecnt[blk * NBUCK + i] = h[i];
  }
  grid.sync();

  // ---- P2: tile_scan (one block per bucket, blocks >= NBUCK idle) ----
  if (blk < NBUCK) {
    int* sm = (int*)shraw;
    int b = blk;
    int i0 = 2 * t, i1 = 2 * t + 1;
    int v0 = (i0 < NSCAT) ? tilecnt[i0 * NBUCK + b] : 0;
    int v1 = (i1 < NSCAT) ? tilecnt[i1 * NBUCK + b] : 0;
    int s = v0 + v1;
    sm[t] = s;
    __syncthreads();
    for (int off = 1; off < 256; off <<= 1) {
      int u = (t >= off) ? sm[t - off] : 0;
      __syncthreads();
      sm[t] += u;
      __syncthreads();
    }
    int ex = sm[t] - s;
    if (i0 < NSCAT) tpre[i0 * NBUCK + b] = ex;
    if (i1 < NSCAT) tpre[i1 * NBUCK + b] = ex + v0;
    if (t == 255) bcnt[b] = sm[255];
  }
  grid.sync();

  // ---- P3: bucket_base (block 0 only) ----
  if (blk == 0) {
    int* sm = (int*)shraw;
    int v = (t < NBUCK) ? bcnt[t] : 0;
    sm[t] = v;
    __syncthreads();
    for (int off = 1; off < 256; off <<= 1) {
      int u = (t >= off) ? sm[t - off] : 0;
      __syncthreads();
      sm[t] += u;
      __syncthreads();
    }
    if (t < NBUCK) bbase[t] = sm[t] - v;
  }
  grid.sync();

  // ---- P4: bucket_scatter (one block per tile) ----
  {
    int* lbase = (int*)shraw;
    int* gb = lbase + NBUCK;
    int* lcur = gb + NBUCK;
    int* ssc = lcur + NBUCK;
    unsigned* stage = (unsigned*)(ssc + 256);
    int tile = blk;
    int base = tile * TILE;
    int cntTile = NE - base; if (cntTile > TILE) cntTile = TILE;
    int h = (t < NBUCK) ? tilecnt[tile * NBUCK + t] : 0;
    ssc[t] = h;
    __syncthreads();
    for (int off = 1; off < 256; off <<= 1) {
      int u = (t >= off) ? ssc[t - off] : 0;
      __syncthreads();
      ssc[t] += u;
      __syncthreads();
    }
    if (t < NBUCK) {
      int ex = ssc[t] - h;
      lbase[t] = ex;
      lcur[t] = ex;
      gb[t] = bbase[t] + tpre[tile * NBUCK + t];
    }
    __syncthreads();
    for (int e = base + t; e < base + cntTile; e += 256) {
      int s = ei[e];
      int d = ei[NE + e];
      int b = d >> 8;
      int pos = atomicAdd(&lcur[b], 1);
      stage[pos] = ((unsigned)(d & 255) << 16) | (unsigned)s;
    }
    __syncthreads();
    for (int i = t; i < cntTile; i += 256) {
      int lo = 0, hi = NBUCK - 1;
      while (lo < hi) {
        int mid = (lo + hi + 1) >> 1;
        if (lbase[mid] <= i) lo = mid; else hi = mid - 1;
      }
      ebuf[gb[lo] + (i - lbase[lo])] = stage[i];
    }
  }
  grid.sync();

  // ---- P5: bucket_csr (one block per bucket) ----
  if (blk < NBUCK) {
    int* cnt = (int*)shraw;
    int* cur = cnt + 256;
    int* sums = cur + 256;
    int b = blk;
    int node0 = b << 8;
    cnt[t] = 0;
    __syncthreads();
    int g0 = bbase[b], g1 = g0 + bcnt[b];
    for (int i = g0 + t; i < g1; i += 256) atomicAdd(&cnt[ebuf[i] >> 16], 1);
    __syncthreads();
    int c = cnt[t];
    sums[t] = c;
    __syncthreads();
    for (int off = 1; off < 256; off <<= 1) {
      int u = (t >= off) ? sums[t - off] : 0;
      __syncthreads();
      sums[t] += u;
      __syncthreads();
    }
    int ex = sums[t] - c;
    cur[t] = ex;
    int node = node0 + t;
    if (node < NN) {
      offs[node] = g0 + ex;
      dinv[node] = rsqrtf((float)(c + 1));
    }
    __syncthreads();
    for (int i = g0 + t; i < g1; i += 256) {
      unsigned v = ebuf[i];
      int pos = atomicAdd(&cur[v >> 16], 1);
      col[g0 + pos] = (int)(v & 0xffffu);
    }
    if (b == 0 && t == 0) offs[NN] = NE;
  }
  grid.sync();

  // ---- P6: post_csr (grid-stride; body verbatim) ----
  for (int id = blk * 256 + t; id < NN * 32 + NN; id += GTH) {
    if (id < NN * 32) {
      float dd = dinv[id >> 5];
      float4 v = ((const float4*)x)[id];
      ushort4 o;
      o.x = bf16_rtne(v.x * dd);
      o.y = bf16_rtne(v.y * dd);
      o.z = bf16_rtne(v.z * dd);
      o.w = bf16_rtne(v.w * dd);
      ((ushort4*)xsb)[id] = o;
    } else {
      int d = id - NN * 32;
      float s = 0.f;
      int end = offs[d + 1];
      for (int p = offs[d]; p < end; ++p) s += dinv[col[p]];
      float dd = dinv[d];
      Svec[d] = dd * (dd + s);
    }
  }
}

// Wave per node; 32 lanes x 4 bf16 (uint2) cover the 128-wide row; two
// 32-lane halves take alternating edges; main tier = 8 edges/half
// (16 row-loads in flight per wave), then 2- and 1-edge tails.
// MODE 0 (layer1): out = dd*(self+sum) -> split bf16 hi/lo (for GEMM A).
// MODE 1 (layer2): out = prelu(dd*(self+sum)+b, a) -> fp32 final output.
template <int MODE>
__global__ __launch_bounds__(256) void agg_kernel(
    const unsigned short* __restrict__ in, const float* __restrict__ dinv,
    const int* __restrict__ offs, const int* __restrict__ col,
    const float* __restrict__ bias, const float* __restrict__ alpha,
    unsigned short* __restrict__ outhi, unsigned short* __restrict__ outlo,
    float* __restrict__ outf) {
  const uint2* inb = (const uint2*)in;  // row = 32 uint2 (128 bf16)
  int t = threadIdx.x;
  int node = blockIdx.x * 4 + (t >> 6);
  int lane = t & 63;
  int r = lane & 31;
  int half = lane >> 5;
  int beg = offs[node], end = offs[node + 1];

  float4 a0 = make_float4(0.f, 0.f, 0.f, 0.f);
  float4 a1 = make_float4(0.f, 0.f, 0.f, 0.f);
  float4 a2 = make_float4(0.f, 0.f, 0.f, 0.f);
  float4 a3 = make_float4(0.f, 0.f, 0.f, 0.f);
  int p = beg + half;
  for (; p + 14 < end; p += 16) {  // 8 edges per half-wave
    int s0 = col[p];      int s1 = col[p + 2];
    int s2 = col[p + 4];  int s3 = col[p + 6];
    int s4 = col[p + 8];  int s5 = col[p + 10];
    int s6 = col[p + 12]; int s7 = col[p + 14];
    uint2 v0 = inb[(size_t)s0 * 32 + r];
    uint2 v1 = inb[(size_t)s1 * 32 + r];
    uint2 v2 = inb[(size_t)s2 * 32 + r];
    uint2 v3 = inb[(size_t)s3 * 32 + r];
    uint2 v4 = inb[(size_t)s4 * 32 + r];
    uint2 v5 = inb[(size_t)s5 * 32 + r];
    uint2 v6 = inb[(size_t)s6 * 32 + r];
    uint2 v7 = inb[(size_t)s7 * 32 + r];
    a0.x += bflo(v0.x); a0.y += bfhi(v0.x); a0.z += bflo(v0.y); a0.w += bfhi(v0.y);
    a1.x += bflo(v1.x); a1.y += bfhi(v1.x); a1.z += bflo(v1.y); a1.w += bfhi(v1.y);
    a2.x += bflo(v2.x); a2.y += bfhi(v2.x); a2.z += bflo(v2.y); a2.w += bfhi(v2.y);
    a3.x += bflo(v3.x); a3.y += bfhi(v3.x); a3.z += bflo(v3.y); a3.w += bfhi(v3.y);
    a0.x += bflo(v4.x); a0.y += bfhi(v4.x); a0.z += bflo(v4.y); a0.w += bfhi(v4.y);
    a1.x += bflo(v5.x); a1.y += bfhi(v5.x); a1.z += bflo(v5.y); a1.w += bfhi(v5.y);
    a2.x += bflo(v6.x); a2.y += bfhi(v6.x); a2.z += bflo(v6.y); a2.w += bfhi(v6.y);
    a3.x += bflo(v7.x); a3.y += bfhi(v7.x); a3.z += bflo(v7.y); a3.w += bfhi(v7.y);
  }
  for (; p + 2 < end; p += 4) {  // 2 edges
    int s0 = col[p];
    int s1 = col[p + 2];
    uint2 v0 = inb[(size_t)s0 * 32 + r];
    uint2 v1 = inb[(size_t)s1 * 32 + r];
    a0.x += bflo(v0.x); a0.y += bfhi(v0.x); a0.z += bflo(v0.y); a0.w += bfhi(v0.y);
    a1.x += bflo(v1.x); a1.y += bfhi(v1.x); a1.z += bflo(v1.y); a1.w += bfhi(v1.y);
  }
  if (p < end) {
    uint2 v0 = inb[(size_t)col[p] * 32 + r];
    a0.x += bflo(v0.x); a0.y += bfhi(v0.x); a0.z += bflo(v0.y); a0.w += bfhi(v0.y);
  }
  float4 acc = make_float4((a0.x + a1.x) + (a2.x + a3.x), (a0.y + a1.y) + (a2.y + a3.y),
                           (a0.z + a1.z) + (a2.z + a3.z), (a0.w + a1.w) + (a2.w + a3.w));
  acc.x += __shfl_xor(acc.x, 32);
  acc.y += __shfl_xor(acc.y, 32);
  acc.z += __shfl_xor(acc.z, 32);
  acc.w += __shfl_xor(acc.w, 32);

  float dd = dinv[node];
  if (half == 0) {
    uint2 sv = inb[(size_t)node * 32 + r];
    acc.x = dd * (acc.x + bflo(sv.x));
    acc.y = dd * (acc.y + bfhi(sv.x));
    acc.z = dd * (acc.z + bflo(sv.y));
    acc.w = dd * (acc.w + bfhi(sv.y));
    if (MODE == 0) {
      ushort4 h4, l4;
      bsplit(acc.x, h4.x, l4.x);
      bsplit(acc.y, h4.y, l4.y);
      bsplit(acc.z, h4.z, l4.z);
      bsplit(acc.w, h4.w, l4.w);
      ((ushort4*)outhi)[(size_t)node * 32 + r] = h4;
      ((ushort4*)outlo)[(size_t)node * 32 + r] = l4;
    } else {
      float4 b = ((const float4*)bias)[r];
      float4 al = ((const float4*)alpha)[r];
      acc.x += b.x; acc.y += b.y; acc.z += b.z; acc.w += b.w;
      acc.x = (acc.x >= 0.f) ? acc.x : al.x * acc.x;
      acc.y = (acc.y >= 0.f) ? acc.y : al.y * acc.y;
      acc.z = (acc.z >= 0.f) ? acc.z : al.z * acc.z;
      acc.w = (acc.w >= 0.f) ? acc.w : al.w * acc.w;
      ((float4*)outf)[(size_t)node * 32 + r] = acc;
    }
  }
}

// Fused split-bf16 MFMA GEMM1+GEMM2 (R10-exact, best verified). Each wave
// owns 16 rows and a private 16KB swizzled LDS tile for the h1 bounce.
__global__ __launch_bounds__(256) void gemm_fused_kernel(
    const unsigned short* __restrict__ Ahi, const unsigned short* __restrict__ Alo,
    const unsigned short* __restrict__ B1hi, const unsigned short* __restrict__ B1lo,
    const unsigned short* __restrict__ B2hi, const unsigned short* __restrict__ B2lo,
    const float* __restrict__ Svec, const float* __restrict__ cvec,
    const float* __restrict__ bias, const float* __restrict__ alpha,
    const float* __restrict__ dinv, unsigned short* __restrict__ h2b) {
  constexpr int K1 = 128, KC1 = 4, NT1 = 16;   // 128 -> 256
  constexpr int KC2 = 8, NT2 = 8;              // 256 -> 128
  __shared__ __attribute__((aligned(16))) char smem[4 * 16384];

  int wave = threadIdx.x >> 6;
  int lane = threadIdx.x & 63;
  int row0 = blockIdx.x * 64 + wave * 16;
  if (row0 >= NN) return;  // NN % 16 == 0: live waves always have 16 full rows
  int m = lane & 15, quad = lane >> 4;
  char* wb = smem + wave * 16384;  // [0,8192)=hi, [8192,16384)=lo

  // ---- phase 1: GEMM1 ----
  short8 ah[KC1], al[KC1];
  const unsigned short* ap = Ahi + (size_t)(row0 + m) * K1 + quad * 8;
  const unsigned short* alp = Alo + (size_t)(row0 + m) * K1 + quad * 8;
#pragma unroll
  for (int c = 0; c < KC1; ++c) {
    ah[c] = *(const short8*)(ap + c * 32);
    al[c] = *(const short8*)(alp + c * 32);
  }
  float sv[4];
#pragma unroll
  for (int i = 0; i < 4; ++i) sv[i] = Svec[row0 + quad * 4 + i];

#pragma unroll 1
  for (int nt = 0; nt < NT1; ++nt) {
    floatx4 acc = {0.f, 0.f, 0.f, 0.f};
#pragma unroll
    for (int c = 0; c < KC1; ++c) {
      short8 bh = *(const short8*)(B1hi + ((size_t)(nt * KC1 + c) * 64 + lane) * 8);
      short8 bl = *(const short8*)(B1lo + ((size_t)(nt * KC1 + c) * 64 + lane) * 8);
      acc = __builtin_amdgcn_mfma_f32_16x16x32_bf16(ah[c], bh, acc, 0, 0, 0);
      acc = __builtin_amdgcn_mfma_f32_16x16x32_bf16(ah[c], bl, acc, 0, 0, 0);
      acc = __builtin_amdgcn_mfma_f32_16x16x32_bf16(al[c], bh, acc, 0, 0, 0);
    }
    int c0 = nt * 16 + m;
    float cv = cvec[c0], bb = bias[c0], aa = alpha[c0];
#pragma unroll
    for (int i = 0; i < 4; ++i) {
      float v = acc[i] + sv[i] * cv + bb;
      v = (v >= 0.f) ? v : aa * v;
      unsigned short hi, lo;
      bsplit(v, hi, lo);
      int row16 = quad * 4 + i;
      int off = row16 * 512 + ((c0 * 2) ^ ((row16 & 7) << 4));
      *(unsigned short*)(wb + off) = hi;
      *(unsigned short*)(wb + 8192 + off) = lo;
    }
  }

  // ---- phase 2: GEMM2 (wave-local LDS; compiler orders ds_write->ds_read) ----
  short8 ah2[KC2], al2[KC2];
#pragma unroll
  for (int c = 0; c < KC2; ++c) {
    int off = m * 512 + ((c * 64 + quad * 16) ^ ((m & 7) << 4));
    ah2[c] = *(const short8*)(wb + off);
    al2[c] = *(const short8*)(wb + 8192 + off);
  }
  float dv[4];
#pragma unroll
  for (int i = 0; i < 4; ++i) dv[i] = dinv[row0 + quad * 4 + i];

#pragma unroll 1
  for (int nt = 0; nt < NT2; ++nt) {
    floatx4 acc = {0.f, 0.f, 0.f, 0.f};
#pragma unroll
    for (int c = 0; c < KC2; ++c) {
      short8 bh = *(const short8*)(B2hi + ((size_t)(nt * KC2 + c) * 64 + lane) * 8);
      short8 bl = *(const short8*)(B2lo + ((size_t)(nt * KC2 + c) * 64 + lane) * 8);
      acc = __builtin_amdgcn_mfma_f32_16x16x32_bf16(ah2[c], bh, acc, 0, 0, 0);
      acc = __builtin_amdgcn_mfma_f32_16x16x32_bf16(ah2[c], bl, acc, 0, 0, 0);
      acc = __builtin_amdgcn_mfma_f32_16x16x32_bf16(al2[c], bh, acc, 0, 0, 0);
    }
    int c0 = nt * 16 + m;
#pragma unroll
    for (int i = 0; i < 4; ++i) {
      int r = row0 + quad * 4 + i;
      h2b[(size_t)r * 128 + c0] = bf16_rtne(acc[i] * dv[i]);
    }
  }
}

extern "C" void kernel_launch(void* const* d_in, const int* in_sizes, int n_in,
                              void* d_out, int out_size, void* d_ws, size_t ws_size,
                              hipStream_t stream) {
  const float* x = (const float*)d_in[0];
  const int* ei = (const int*)d_in[1];
  const float* idv = (const float*)d_in[2];
  const float* W1 = (const float*)d_in[3];
  const float* b1 = (const float*)d_in[4];
  const float* a1 = (const float*)d_in[5];
  const float* W2 = (const float*)d_in[6];
  const float* b2 = (const float*)d_in[7];
  const float* a2 = (const float*)d_in[8];
  float* out = (float*)d_out;

  char* w = (char*)d_ws;
  size_t off = 0;
  auto alloc = [&](size_t bytes) -> void* {
    void* p = w + off;
    off += bytes;
    off = (off + 255) & ~(size_t)255;
    return p;
  };
  int* tilecnt = (int*)alloc((size_t)NSCAT * NBUCK * 4);
  int* tpre = (int*)alloc((size_t)NSCAT * NBUCK * 4);
  int* bbase = (int*)alloc((size_t)NBUCK * 4);
  int* bcnt = (int*)alloc((size_t)NBUCK * 4);
  unsigned* ebuf = (unsigned*)alloc((size_t)NE * 4);
  float* dinv = (float*)alloc((size_t)NN * 4);
  float* Svec = (float*)alloc((size_t)NN * 4);
  int* offs = (int*)alloc((size_t)(NN + 1) * 4);
  int* col = (int*)alloc((size_t)NE * 4);
  float* cvec = (float*)alloc(256 * 4);
  unsigned short* xsb = (unsigned short*)alloc((size_t)NN * 128 * 2);
  unsigned short* aggxhi = (unsigned short*)alloc((size_t)NN * 128 * 2);
  unsigned short* aggxlo = (unsigned short*)alloc((size_t)NN * 128 * 2);
  unsigned short* h2b = (unsigned short*)alloc((size_t)NN * 128 * 2);
  unsigned short* B1hi = (unsigned short*)alloc(128 * 256 * 2);
  unsigned short* B1lo = (unsigned short*)alloc(128 * 256 * 2);
  unsigned short* B2hi = (unsigned short*)alloc(256 * 128 * 2);
  unsigned short* B2lo = (unsigned short*)alloc(256 * 128 * 2);

  // one cooperative kernel: prep + CSR build + post_csr (grid.sync phases)
  void* args[] = {(void*)&ei, (void*)&x, (void*)&W1, (void*)&W2, (void*)&idv,
                  (void*)&tilecnt, (void*)&tpre, (void*)&bbase, (void*)&bcnt,
                  (void*)&ebuf, (void*)&offs, (void*)&col, (void*)&dinv,
                  (void*)&xsb, (void*)&Svec, (void*)&B1hi, (void*)&B1lo,
                  (void*)&B2hi, (void*)&B2lo, (void*)&cvec};
  hipLaunchCooperativeKernel((void*)build_kernel, dim3(NSCAT), dim3(256),
                             args, 0, stream);

  // layer-1 aggregate (bf16 gather, fp32 accum) -> split bf16 hi/lo
  agg_kernel<0><<<NN / 4, 256, 0, stream>>>(xsb, dinv, offs, col, nullptr, nullptr,
                                            aggxhi, aggxlo, nullptr);

  // fused: h1 = prelu(aggx@W1 + Svec*cvec + b1); h2b = bf16((h1@W2)*dinv)
  gemm_fused_kernel<<<(NN + 63) / 64, 256, 0, stream>>>(
      aggxhi, aggxlo, B1hi, B1lo, B2hi, B2lo, Svec, cvec, b1, a1, dinv, h2b);

  // layer-2 aggregate (bf16 gather) + bias + prelu -> fp32 out
  agg_kernel<1><<<NN / 4, 256, 0, stream>>>(h2b, dinv, offs, col, b2, a2,
                                            nullptr, nullptr, out);
}

// Round 10
// 253.617 us; speedup vs baseline: 1.9041x; 1.9041x over previous
//
#include <hip/hip_runtime.h>

// GCN_72971494359045: 2-layer GCNConv(+self-loops, sym-norm) with PReLU.
// N=50000 nodes, E=800000 edges, dims 128(+8 id)->256->128, all fp32.
//
// R18: R10-exact gemm/aggs (best verified: 256.4us total). R17's coop-kernel
// failed (grid.sync ~45us each on 8 XCDs). Instead, launch-count 10 -> 7 via
// dependency-free merges only:
//  - prep_weights -> tile_count prologue (independent work).
//  - bucket_base deleted; scatter/csr recompute the 196-wide bcnt prefix
//    locally in LDS (~1us).
//  - post_csr split: xsb -> bucket_csr epilogue (own-bucket dinv only,
//    coalesced); Svec -> agg<0> prologue (global dinv ready by then).
// Every per-element formula and FP order unchanged -> absmax canary
// 0.001953125. Determinism preserved.

constexpr int NN = 50000;
constexpr int NE = 800000;
constexpr int NBUCK = 196;   // ceil(NN / 256), bucket = dst >> 8
constexpr int TILE = 2048;   // edges per scatter block
constexpr int NSCAT = (NE + TILE - 1) / TILE;  // 391

typedef __attribute__((ext_vector_type(8))) short short8;
typedef __attribute__((ext_vector_type(4))) float floatx4;

__device__ inline void bsplit(float v, unsigned short& hi, unsigned short& lo) {
  unsigned u = __float_as_uint(v);
  hi = (unsigned short)(u >> 16);
  float rem = v - __uint_as_float(u & 0xffff0000u);
  lo = (unsigned short)(__float_as_uint(rem) >> 16);
}

__device__ inline unsigned short bf16_rtne(float v) {
  unsigned u = __float_as_uint(v);
  return (unsigned short)((u + 0x7fffu + ((u >> 16) & 1u)) >> 16);
}

__device__ inline float bflo(unsigned u) { return __uint_as_float(u << 16); }
__device__ inline float bfhi(unsigned u) { return __uint_as_float(u & 0xffff0000u); }

// Pack W[K x N] (fp32, row-major) into MFMA B-fragment order, split hi/lo.
template <int K, int N>
__device__ inline void pack_one(const float* __restrict__ W, unsigned short* __restrict__ Bhi,
                                unsigned short* __restrict__ Blo, int id) {
  constexpr int KC = K / 32;
  int j = id & 7;
  int lane = (id >> 3) & 63;
  int rest = id >> 9;
  int c = rest % KC;
  int nt = rest / KC;
  int k = c * 32 + (lane >> 4) * 8 + j;
  int n = nt * 16 + (lane & 15);
  unsigned short hi, lo;
  bsplit(W[(size_t)k * N + n], hi, lo);
  Bhi[id] = hi;
  Blo[id] = lo;
}

// --- binned CSR build (deterministic, atomic-free bases) ---

// tile_count + prep_weights prologue (independent; 391*256 covers 65792 ids).
__global__ __launch_bounds__(256) void tile_count_kernel(
    const int* __restrict__ ei, int* __restrict__ tilecnt,
    const float* __restrict__ W1, const float* __restrict__ W2,
    const float* __restrict__ idv,
    unsigned short* __restrict__ B1hi, unsigned short* __restrict__ B1lo,
    unsigned short* __restrict__ B2hi, unsigned short* __restrict__ B2lo,
    float* __restrict__ cvec) {
  __shared__ int h[NBUCK];
  int t = threadIdx.x;
  int id = blockIdx.x * 256 + t;
  if (id < 32768) {
    pack_one<128, 256>(W1, B1hi, B1lo, id);
  } else if (id < 65536) {
    pack_one<256, 128>(W2, B2hi, B2lo, id - 32768);
  } else if (id < 65536 + 256) {
    int m = id - 65536;
    float c = 0.f;
#pragma unroll
    for (int j = 0; j < 8; ++j) c += idv[j] * W1[(128 + j) * 256 + m];
    cvec[m] = c;
  }
  for (int i = t; i < NBUCK; i += 256) h[i] = 0;
  __syncthreads();
  int base = blockIdx.x * TILE;
  int end = base + TILE; if (end > NE) end = NE;
  for (int e = base + t; e < end; e += 256) atomicAdd(&h[ei[NE + e] >> 8], 1);
  __syncthreads();
  for (int i = t; i < NBUCK; i += 256) tilecnt[blockIdx.x * NBUCK + i] = h[i];
}

// One block per bucket: exclusive scan of its count across the 391 tiles.
__global__ __launch_bounds__(256) void tile_scan_a_kernel(const int* __restrict__ tilecnt,
                                                          int* __restrict__ tpre,
                                                          int* __restrict__ bcnt) {
  __shared__ int sm[256];
  int b = blockIdx.x, t = threadIdx.x;
  int i0 = 2 * t, i1 = 2 * t + 1;
  int v0 = (i0 < NSCAT) ? tilecnt[i0 * NBUCK + b] : 0;
  int v1 = (i1 < NSCAT) ? tilecnt[i1 * NBUCK + b] : 0;
  int s = v0 + v1;
  sm[t] = s;
  __syncthreads();
  for (int off = 1; off < 256; off <<= 1) {
    int u = (t >= off) ? sm[t - off] : 0;
    __syncthreads();
    sm[t] += u;
    __syncthreads();
  }
  int ex = sm[t] - s;
  if (i0 < NSCAT) tpre[i0 * NBUCK + b] = ex;
  if (i1 < NSCAT) tpre[i1 * NBUCK + b] = ex + v0;
  if (t == 255) bcnt[b] = sm[255];
}

// Stage tile in LDS grouped by bucket; flush in parallel (binary search for
// owning bucket). Bucket bases recomputed locally from bcnt (196-wide scan).
__global__ __launch_bounds__(256) void bucket_scatter_kernel(
    const int* __restrict__ ei, const int* __restrict__ tilecnt,
    const int* __restrict__ tpre, const int* __restrict__ bcnt,
    unsigned* __restrict__ ebuf) {
  __shared__ int lbase[NBUCK], gb[NBUCK], lcur[NBUCK], ssc[256], bb[256];
  __shared__ unsigned stage[TILE];
  int t = threadIdx.x;
  int tile = blockIdx.x;
  int base = tile * TILE;
  int cntTile = NE - base; if (cntTile > TILE) cntTile = TILE;
  // local bbase: exclusive prefix of bcnt
  int bv = (t < NBUCK) ? bcnt[t] : 0;
  bb[t] = bv;
  __syncthreads();
  for (int off = 1; off < 256; off <<= 1) {
    int u = (t >= off) ? bb[t - off] : 0;
    __syncthreads();
    bb[t] += u;
    __syncthreads();
  }
  int bbase_t = bb[t] - bv;  // valid for t < NBUCK
  int h = (t < NBUCK) ? tilecnt[tile * NBUCK + t] : 0;
  ssc[t] = h;
  __syncthreads();
  for (int off = 1; off < 256; off <<= 1) {
    int u = (t >= off) ? ssc[t - off] : 0;
    __syncthreads();
    ssc[t] += u;
    __syncthreads();
  }
  if (t < NBUCK) {
    int ex = ssc[t] - h;
    lbase[t] = ex;
    lcur[t] = ex;
    gb[t] = bbase_t + tpre[tile * NBUCK + t];
  }
  __syncthreads();
  for (int e = base + t; e < base + cntTile; e += 256) {
    int s = ei[e];
    int d = ei[NE + e];
    int b = d >> 8;
    int pos = atomicAdd(&lcur[b], 1);
    stage[pos] = ((unsigned)(d & 255) << 16) | (unsigned)s;
  }
  __syncthreads();
  for (int i = t; i < cntTile; i += 256) {
    int lo = 0, hi = NBUCK - 1;
    while (lo < hi) {
      int mid = (lo + hi + 1) >> 1;
      if (lbase[mid] <= i) lo = mid; else hi = mid - 1;
    }
    ebuf[gb[lo] + (i - lbase[lo])] = stage[i];
  }
}

// One block per bucket (256 nodes): node histogram -> offs/dinv, scatter col,
// then xsb epilogue for the bucket's nodes (needs only own-bucket dinv).
__global__ __launch_bounds__(256) void bucket_csr_kernel(
    const unsigned* __restrict__ ebuf, const int* __restrict__ bcnt,
    int* __restrict__ offs, int* __restrict__ col, float* __restrict__ dinv,
    const float* __restrict__ x, unsigned short* __restrict__ xsb) {
  __shared__ int cnt[256], cur[256], sums[256];
  __shared__ float dvs[256];
  int b = blockIdx.x, t = threadIdx.x;
  int node0 = b << 8;
  // local bbase: exclusive prefix of bcnt, element b
  int bv = (t < NBUCK) ? bcnt[t] : 0;
  sums[t] = bv;
  __syncthreads();
  for (int off = 1; off < 256; off <<= 1) {
    int u = (t >= off) ? sums[t - off] : 0;
    __syncthreads();
    sums[t] += u;
    __syncthreads();
  }
  int g0 = sums[b] - bcnt[b];
  int g1 = g0 + bcnt[b];
  __syncthreads();
  cnt[t] = 0;
  __syncthreads();
  for (int i = g0 + t; i < g1; i += 256) atomicAdd(&cnt[ebuf[i] >> 16], 1);
  __syncthreads();
  int c = cnt[t];
  sums[t] = c;
  __syncthreads();
  for (int off = 1; off < 256; off <<= 1) {
    int u = (t >= off) ? sums[t - off] : 0;
    __syncthreads();
    sums[t] += u;
    __syncthreads();
  }
  int ex = sums[t] - c;
  cur[t] = ex;
  int node = node0 + t;
  if (node < NN) {
    float dd = rsqrtf((float)(c + 1));
    offs[node] = g0 + ex;
    dinv[node] = dd;
    dvs[t] = dd;
  }
  __syncthreads();
  for (int i = g0 + t; i < g1; i += 256) {
    unsigned v = ebuf[i];
    int pos = atomicAdd(&cur[v >> 16], 1);
    col[g0 + pos] = (int)(v & 0xffffu);
  }
  if (b == 0 && t == 0) offs[NN] = NE;
  // xsb epilogue: 8 nodes per iteration, coalesced float4 (same formula
  // and per-element FP op as the former post_csr).
  const float4* x4 = (const float4*)x;
  ushort4* xb4 = (ushort4*)xsb;
#pragma unroll 1
  for (int i = 0; i < 32; ++i) {
    int idx = i * 256 + t;
    int nl = idx >> 5, el = idx & 31;
    int n2 = node0 + nl;
    if (n2 < NN) {
      float dd = dvs[nl];
      float4 v = x4[(size_t)n2 * 32 + el];
      ushort4 o;
      o.x = bf16_rtne(v.x * dd);
      o.y = bf16_rtne(v.y * dd);
      o.z = bf16_rtne(v.z * dd);
      o.w = bf16_rtne(v.w * dd);
      xb4[(size_t)n2 * 32 + el] = o;
    }
  }
}

// Wave per node; 32 lanes x 4 bf16 (uint2) cover the 128-wide row; two
// 32-lane halves take alternating edges; main tier = 8 edges/half
// (16 row-loads in flight per wave), then 2- and 1-edge tails.
// MODE 0 (layer1): Svec prologue (body verbatim from post_csr), then
//                  out = dd*(self+sum) -> split bf16 hi/lo (for GEMM A).
// MODE 1 (layer2): out = prelu(dd*(self+sum)+b, a) -> fp32 final output.
template <int MODE>
__global__ __launch_bounds__(256) void agg_kernel(
    const unsigned short* __restrict__ in, const float* __restrict__ dinv,
    const int* __restrict__ offs, const int* __restrict__ col,
    const float* __restrict__ bias, const float* __restrict__ alpha,
    unsigned short* __restrict__ outhi, unsigned short* __restrict__ outlo,
    float* __restrict__ outf, float* __restrict__ Svec) {
  int t = threadIdx.x;
  if (MODE == 0) {  // Svec prologue: blocks 0..195 cover all nodes
    int d = blockIdx.x * 256 + t;
    if (d < NN) {
      float s = 0.f;
      int end2 = offs[d + 1];
      for (int p2 = offs[d]; p2 < end2; ++p2) s += dinv[col[p2]];
      float dd2 = dinv[d];
      Svec[d] = dd2 * (dd2 + s);
    }
  }
  const uint2* inb = (const uint2*)in;  // row = 32 uint2 (128 bf16)
  int node = blockIdx.x * 4 + (t >> 6);
  int lane = t & 63;
  int r = lane & 31;
  int half = lane >> 5;
  int beg = offs[node], end = offs[node + 1];

  float4 a0 = make_float4(0.f, 0.f, 0.f, 0.f);
  float4 a1 = make_float4(0.f, 0.f, 0.f, 0.f);
  float4 a2 = make_float4(0.f, 0.f, 0.f, 0.f);
  float4 a3 = make_float4(0.f, 0.f, 0.f, 0.f);
  int p = beg + half;
  for (; p + 14 < end; p += 16) {  // 8 edges per half-wave
    int s0 = col[p];      int s1 = col[p + 2];
    int s2 = col[p + 4];  int s3 = col[p + 6];
    int s4 = col[p + 8];  int s5 = col[p + 10];
    int s6 = col[p + 12]; int s7 = col[p + 14];
    uint2 v0 = inb[(size_t)s0 * 32 + r];
    uint2 v1 = inb[(size_t)s1 * 32 + r];
    uint2 v2 = inb[(size_t)s2 * 32 + r];
    uint2 v3 = inb[(size_t)s3 * 32 + r];
    uint2 v4 = inb[(size_t)s4 * 32 + r];
    uint2 v5 = inb[(size_t)s5 * 32 + r];
    uint2 v6 = inb[(size_t)s6 * 32 + r];
    uint2 v7 = inb[(size_t)s7 * 32 + r];
    a0.x += bflo(v0.x); a0.y += bfhi(v0.x); a0.z += bflo(v0.y); a0.w += bfhi(v0.y);
    a1.x += bflo(v1.x); a1.y += bfhi(v1.x); a1.z += bflo(v1.y); a1.w += bfhi(v1.y);
    a2.x += bflo(v2.x); a2.y += bfhi(v2.x); a2.z += bflo(v2.y); a2.w += bfhi(v2.y);
    a3.x += bflo(v3.x); a3.y += bfhi(v3.x); a3.z += bflo(v3.y); a3.w += bfhi(v3.y);
    a0.x += bflo(v4.x); a0.y += bfhi(v4.x); a0.z += bflo(v4.y); a0.w += bfhi(v4.y);
    a1.x += bflo(v5.x); a1.y += bfhi(v5.x); a1.z += bflo(v5.y); a1.w += bfhi(v5.y);
    a2.x += bflo(v6.x); a2.y += bfhi(v6.x); a2.z += bflo(v6.y); a2.w += bfhi(v6.y);
    a3.x += bflo(v7.x); a3.y += bfhi(v7.x); a3.z += bflo(v7.y); a3.w += bfhi(v7.y);
  }
  for (; p + 2 < end; p += 4) {  // 2 edges
    int s0 = col[p];
    int s1 = col[p + 2];
    uint2 v0 = inb[(size_t)s0 * 32 + r];
    uint2 v1 = inb[(size_t)s1 * 32 + r];
    a0.x += bflo(v0.x); a0.y += bfhi(v0.x); a0.z += bflo(v0.y); a0.w += bfhi(v0.y);
    a1.x += bflo(v1.x); a1.y += bfhi(v1.x); a1.z += bflo(v1.y); a1.w += bfhi(v1.y);
  }
  if (p < end) {
    uint2 v0 = inb[(size_t)col[p] * 32 + r];
    a0.x += bflo(v0.x); a0.y += bfhi(v0.x); a0.z += bflo(v0.y); a0.w += bfhi(v0.y);
  }
  float4 acc = make_float4((a0.x + a1.x) + (a2.x + a3.x), (a0.y + a1.y) + (a2.y + a3.y),
                           (a0.z + a1.z) + (a2.z + a3.z), (a0.w + a1.w) + (a2.w + a3.w));
  acc.x += __shfl_xor(acc.x, 32);
  acc.y += __shfl_xor(acc.y, 32);
  acc.z += __shfl_xor(acc.z, 32);
  acc.w += __shfl_xor(acc.w, 32);

  float dd = dinv[node];
  if (half == 0) {
    uint2 sv = inb[(size_t)node * 32 + r];
    acc.x = dd * (acc.x + bflo(sv.x));
    acc.y = dd * (acc.y + bfhi(sv.x));
    acc.z = dd * (acc.z + bflo(sv.y));
    acc.w = dd * (acc.w + bfhi(sv.y));
    if (MODE == 0) {
      ushort4 h4, l4;
      bsplit(acc.x, h4.x, l4.x);
      bsplit(acc.y, h4.y, l4.y);
      bsplit(acc.z, h4.z, l4.z);
      bsplit(acc.w, h4.w, l4.w);
      ((ushort4*)outhi)[(size_t)node * 32 + r] = h4;
      ((ushort4*)outlo)[(size_t)node * 32 + r] = l4;
    } else {
      float4 b = ((const float4*)bias)[r];
      float4 al = ((const float4*)alpha)[r];
      acc.x += b.x; acc.y += b.y; acc.z += b.z; acc.w += b.w;
      acc.x = (acc.x >= 0.f) ? acc.x : al.x * acc.x;
      acc.y = (acc.y >= 0.f) ? acc.y : al.y * acc.y;
      acc.z = (acc.z >= 0.f) ? acc.z : al.z * acc.z;
      acc.w = (acc.w >= 0.f) ? acc.w : al.w * acc.w;
      ((float4*)outf)[(size_t)node * 32 + r] = acc;
    }
  }
}

// Fused split-bf16 MFMA GEMM1+GEMM2 (R10-exact, best verified). Each wave
// owns 16 rows and a private 16KB swizzled LDS tile for the h1 bounce.
__global__ __launch_bounds__(256) void gemm_fused_kernel(
    const unsigned short* __restrict__ Ahi, const unsigned short* __restrict__ Alo,
    const unsigned short* __restrict__ B1hi, const unsigned short* __restrict__ B1lo,
    const unsigned short* __restrict__ B2hi, const unsigned short* __restrict__ B2lo,
    const float* __restrict__ Svec, const float* __restrict__ cvec,
    const float* __restrict__ bias, const float* __restrict__ alpha,
    const float* __restrict__ dinv, unsigned short* __restrict__ h2b) {
  constexpr int K1 = 128, KC1 = 4, NT1 = 16;   // 128 -> 256
  constexpr int KC2 = 8, NT2 = 8;              // 256 -> 128
  __shared__ __attribute__((aligned(16))) char smem[4 * 16384];

  int wave = threadIdx.x >> 6;
  int lane = threadIdx.x & 63;
  int row0 = blockIdx.x * 64 + wave * 16;
  if (row0 >= NN) return;  // NN % 16 == 0: live waves always have 16 full rows
  int m = lane & 15, quad = lane >> 4;
  char* wb = smem + wave * 16384;  // [0,8192)=hi, [8192,16384)=lo

  // ---- phase 1: GEMM1 ----
  short8 ah[KC1], al[KC1];
  const unsigned short* ap = Ahi + (size_t)(row0 + m) * K1 + quad * 8;
  const unsigned short* alp = Alo + (size_t)(row0 + m) * K1 + quad * 8;
#pragma unroll
  for (int c = 0; c < KC1; ++c) {
    ah[c] = *(const short8*)(ap + c * 32);
    al[c] = *(const short8*)(alp + c * 32);
  }
  float sv[4];
#pragma unroll
  for (int i = 0; i < 4; ++i) sv[i] = Svec[row0 + quad * 4 + i];

#pragma unroll 1
  for (int nt = 0; nt < NT1; ++nt) {
    floatx4 acc = {0.f, 0.f, 0.f, 0.f};
#pragma unroll
    for (int c = 0; c < KC1; ++c) {
      short8 bh = *(const short8*)(B1hi + ((size_t)(nt * KC1 + c) * 64 + lane) * 8);
      short8 bl = *(const short8*)(B1lo + ((size_t)(nt * KC1 + c) * 64 + lane) * 8);
      acc = __builtin_amdgcn_mfma_f32_16x16x32_bf16(ah[c], bh, acc, 0, 0, 0);
      acc = __builtin_amdgcn_mfma_f32_16x16x32_bf16(ah[c], bl, acc, 0, 0, 0);
      acc = __builtin_amdgcn_mfma_f32_16x16x32_bf16(al[c], bh, acc, 0, 0, 0);
    }
    int c0 = nt * 16 + m;
    float cv = cvec[c0], bb = bias[c0], aa = alpha[c0];
#pragma unroll
    for (int i = 0; i < 4; ++i) {
      float v = acc[i] + sv[i] * cv + bb;
      v = (v >= 0.f) ? v : aa * v;
      unsigned short hi, lo;
      bsplit(v, hi, lo);
      int row16 = quad * 4 + i;
      int off = row16 * 512 + ((c0 * 2) ^ ((row16 & 7) << 4));
      *(unsigned short*)(wb + off) = hi;
      *(unsigned short*)(wb + 8192 + off) = lo;
    }
  }

  // ---- phase 2: GEMM2 (wave-local LDS; compiler orders ds_write->ds_read) ----
  short8 ah2[KC2], al2[KC2];
#pragma unroll
  for (int c = 0; c < KC2; ++c) {
    int off = m * 512 + ((c * 64 + quad * 16) ^ ((m & 7) << 4));
    ah2[c] = *(const short8*)(wb + off);
    al2[c] = *(const short8*)(wb + 8192 + off);
  }
  float dv[4];
#pragma unroll
  for (int i = 0; i < 4; ++i) dv[i] = dinv[row0 + quad * 4 + i];

#pragma unroll 1
  for (int nt = 0; nt < NT2; ++nt) {
    floatx4 acc = {0.f, 0.f, 0.f, 0.f};
#pragma unroll
    for (int c = 0; c < KC2; ++c) {
      short8 bh = *(const short8*)(B2hi + ((size_t)(nt * KC2 + c) * 64 + lane) * 8);
      short8 bl = *(const short8*)(B2lo + ((size_t)(nt * KC2 + c) * 64 + lane) * 8);
      acc = __builtin_amdgcn_mfma_f32_16x16x32_bf16(ah2[c], bh, acc, 0, 0, 0);
      acc = __builtin_amdgcn_mfma_f32_16x16x32_bf16(ah2[c], bl, acc, 0, 0, 0);
      acc = __builtin_amdgcn_mfma_f32_16x16x32_bf16(al2[c], bh, acc, 0, 0, 0);
    }
    int c0 = nt * 16 + m;
#pragma unroll
    for (int i = 0; i < 4; ++i) {
      int r = row0 + quad * 4 + i;
      h2b[(size_t)r * 128 + c0] = bf16_rtne(acc[i] * dv[i]);
    }
  }
}

extern "C" void kernel_launch(void* const* d_in, const int* in_sizes, int n_in,
                              void* d_out, int out_size, void* d_ws, size_t ws_size,
                              hipStream_t stream) {
  const float* x = (const float*)d_in[0];
  const int* ei = (const int*)d_in[1];
  const float* idv = (const float*)d_in[2];
  const float* W1 = (const float*)d_in[3];
  const float* b1 = (const float*)d_in[4];
  const float* a1 = (const float*)d_in[5];
  const float* W2 = (const float*)d_in[6];
  const float* b2 = (const float*)d_in[7];
  const float* a2 = (const float*)d_in[8];
  float* out = (float*)d_out;

  char* w = (char*)d_ws;
  size_t off = 0;
  auto alloc = [&](size_t bytes) -> void* {
    void* p = w + off;
    off += bytes;
    off = (off + 255) & ~(size_t)255;
    return p;
  };
  int* tilecnt = (int*)alloc((size_t)NSCAT * NBUCK * 4);
  int* tpre = (int*)alloc((size_t)NSCAT * NBUCK * 4);
  int* bcnt = (int*)alloc((size_t)NBUCK * 4);
  unsigned* ebuf = (unsigned*)alloc((size_t)NE * 4);
  float* dinv = (float*)alloc((size_t)NN * 4);
  float* Svec = (float*)alloc((size_t)NN * 4);
  int* offs = (int*)alloc((size_t)(NN + 1) * 4);
  int* col = (int*)alloc((size_t)NE * 4);
  float* cvec = (float*)alloc(256 * 4);
  unsigned short* xsb = (unsigned short*)alloc((size_t)NN * 128 * 2);
  unsigned short* aggxhi = (unsigned short*)alloc((size_t)NN * 128 * 2);
  unsigned short* aggxlo = (unsigned short*)alloc((size_t)NN * 128 * 2);
  unsigned short* h2b = (unsigned short*)alloc((size_t)NN * 128 * 2);
  unsigned short* B1hi = (unsigned short*)alloc(128 * 256 * 2);
  unsigned short* B1lo = (unsigned short*)alloc(128 * 256 * 2);
  unsigned short* B2hi = (unsigned short*)alloc(256 * 128 * 2);
  unsigned short* B2lo = (unsigned short*)alloc(256 * 128 * 2);

  // CSR build + weight prep (7 launches total)
  tile_count_kernel<<<NSCAT, 256, 0, stream>>>(ei, tilecnt, W1, W2, idv,
                                               B1hi, B1lo, B2hi, B2lo, cvec);
  tile_scan_a_kernel<<<NBUCK, 256, 0, stream>>>(tilecnt, tpre, bcnt);
  bucket_scatter_kernel<<<NSCAT, 256, 0, stream>>>(ei, tilecnt, tpre, bcnt, ebuf);
  bucket_csr_kernel<<<NBUCK, 256, 0, stream>>>(ebuf, bcnt, offs, col, dinv, x, xsb);

  // layer-1 aggregate (+ Svec prologue) -> split bf16 hi/lo
  agg_kernel<0><<<NN / 4, 256, 0, stream>>>(xsb, dinv, offs, col, nullptr, nullptr,
                                            aggxhi, aggxlo, nullptr, Svec);

  // fused: h1 = prelu(aggx@W1 + Svec*cvec + b1); h2b = bf16((h1@W2)*dinv)
  gemm_fused_kernel<<<(NN + 63) / 64, 256, 0, stream>>>(
      aggxhi, aggxlo, B1hi, B1lo, B2hi, B2lo, Svec, cvec, b1, a1, dinv, h2b);

  // layer-2 aggregate (bf16 gather) + bias + prelu -> fp32 out
  agg_kernel<1><<<NN / 4, 256, 0, stream>>>(h2b, dinv, offs, col, b2, a2,
                                            nullptr, nullptr, out, nullptr);
}